// Round 3
// baseline (109.836 us; speedup 1.0000x reference)
//
#include <hip/hip_runtime.h>

// NeRF fused render: B rays x S samples, MLP 3->64(relu)->4(exp), alpha composite.
// R3: packed-fp32 inner loop (v_pk_fma_f32). acc is [channel][sample-pair] of
// float2; per h per sample-pair: 1 pk_fma (hidden) + 2 max + 4 pk_fma (layer 2).

typedef float v2f __attribute__((ext_vector_type(2)));

constexpr int S_TOTAL = 128;
constexpr int TPR     = 16;            // threads (lanes) per ray
constexpr int SPT     = S_TOTAL / TPR; // 8 samples per thread
constexpr int NPAIR   = SPT / 2;       // 4 sample-pairs per thread
constexpr int BLOCK   = 256;
constexpr int RPB     = BLOCK / TPR;   // 16 rays per block
constexpr int H       = 64;

__global__ __launch_bounds__(BLOCK, 8)
void nerf_fused(const float* __restrict__ origins,
                const float* __restrict__ directions,
                const float* __restrict__ nearp,
                const float* __restrict__ farp,
                const float* __restrict__ W1,   // [3][64]
                const float* __restrict__ b1,   // [64]
                const float* __restrict__ W2,   // [64][4]
                const float* __restrict__ b2,   // [4]
                float* __restrict__ out,        // [B][3]
                int B)
{
    // per-(ray,h) affine fold: ABs[r][h] = {A,B} with pre_h(m) = A + m*B
    __shared__ float ABs[RPB][H + 1][2];
    __shared__ v2f   W2s[H][2];          // [h] -> {w2[0],w2[1]},{w2[2],w2[3]}
    __shared__ float b2s[4];

    const int tid  = threadIdx.x;
    const int ray0 = blockIdx.x * RPB;

    if (tid < H) {
        W2s[tid][0] = (v2f){W2[tid * 4 + 0], W2[tid * 4 + 1]};
        W2s[tid][1] = (v2f){W2[tid * 4 + 2], W2[tid * 4 + 3]};
    }
    if (tid < 4) b2s[tid] = b2[tid];

#pragma unroll
    for (int idx = tid; idx < RPB * H; idx += BLOCK) {
        const int r   = idx >> 6;        // / H
        const int h   = idx & (H - 1);
        const int ray = ray0 + r;
        const float o0 = origins[ray * 3 + 0];
        const float o1 = origins[ray * 3 + 1];
        const float o2 = origins[ray * 3 + 2];
        float d0 = directions[ray * 3 + 0];
        float d1 = directions[ray * 3 + 1];
        float d2 = directions[ray * 3 + 2];
        const float nrm  = sqrtf(d0 * d0 + d1 * d1 + d2 * d2);
        const float rinv = 1.0f / fmaxf(nrm, 1e-12f);
        d0 *= rinv; d1 *= rinv; d2 *= rinv;
        const float w0 = W1[0 * H + h];
        const float w1 = W1[1 * H + h];
        const float w2 = W1[2 * H + h];
        ABs[r][h][0] = fmaf(o2, w2, fmaf(o1, w1, fmaf(o0, w0, b1[h])));
        ABs[r][h][1] = fmaf(d2, w2, fmaf(d1, w1, d0 * w0));
    }
    __syncthreads();

    const int sub  = tid & (TPR - 1);    // lane within ray group
    const int rloc = tid >> 4;           // local ray index (log2(TPR)=4)
    const int ray  = ray0 + rloc;

    const float nr    = nearp[0];
    const float fr    = farp[0];
    const float delta = (fr - nr) * (1.0f / (float)S_TOTAL);

    // sample-pair midpoints: mp[p] = {m(2p), m(2p+1)} for this lane's chunk
    v2f mp[NPAIR];
#pragma unroll
    for (int p = 0; p < NPAIR; ++p) {
        const float s0 = (float)(sub * SPT + 2 * p) + 0.5f;
        mp[p] = (v2f){fmaf(s0, delta, nr), fmaf(s0 + 1.0f, delta, nr)};
    }

    // acc[c][p]: channel c for sample pair p
    v2f acc[4][NPAIR];
#pragma unroll
    for (int c = 0; c < 4; ++c) {
        const v2f bc = (v2f){b2s[c], b2s[c]};
#pragma unroll
        for (int p = 0; p < NPAIR; ++p) acc[c][p] = bc;
    }

    const v2f vzero = (v2f){0.0f, 0.0f};

#pragma unroll 8
    for (int h = 0; h < H; ++h) {
        const v2f ab  = *reinterpret_cast<const v2f*>(&ABs[rloc][h][0]); // {A,B}
        const v2f w01 = W2s[h][0];
        const v2f w23 = W2s[h][1];
        const v2f Ah = ab.xx, Bh = ab.yy;
        const v2f w0 = w01.xx, w1 = w01.yy, w2 = w23.xx, w3 = w23.yy;
#pragma unroll
        for (int p = 0; p < NPAIR; ++p) {
            v2f hp = __builtin_elementwise_fma(mp[p], Bh, Ah);   // v_pk_fma_f32
            hp = __builtin_elementwise_max(hp, vzero);           // 2x v_max_f32
            acc[0][p] = __builtin_elementwise_fma(hp, w0, acc[0][p]);
            acc[1][p] = __builtin_elementwise_fma(hp, w1, acc[1][p]);
            acc[2][p] = __builtin_elementwise_fma(hp, w2, acc[2][p]);
            acc[3][p] = __builtin_elementwise_fma(hp, w3, acc[3][p]);
        }
    }

    // local (in-order) composite over this lane's 8 samples
    float Tloc = 1.0f, orr = 0.0f, og = 0.0f, ob = 0.0f;
#pragma unroll
    for (int p = 0; p < NPAIR; ++p) {
#pragma unroll
        for (int half = 0; half < 2; ++half) {
            const float sg = half ? acc[3][p].y : acc[3][p].x;
            const float cr = half ? acc[0][p].y : acc[0][p].x;
            const float cg = half ? acc[1][p].y : acc[1][p].x;
            const float cb = half ? acc[2][p].y : acc[2][p].x;
            const float sig = __expf(sg);
            const float e   = __expf(-sig * delta);  // = 1 - alpha
            Tloc *= e;                               // inclusive cumprod
            const float w = Tloc * (1.0f - e);       // T * alpha
            orr = fmaf(w, __expf(cr), orr);
            og  = fmaf(w, __expf(cg), og);
            ob  = fmaf(w, __expf(cb), ob);
        }
    }

    // stitch across the 16 lanes of this ray:
    // inclusive scan-product of Tloc, then exclusive prefix for scaling
    float scan = Tloc;
#pragma unroll
    for (int off = 1; off < TPR; off <<= 1) {
        const float v = __shfl_up(scan, off, TPR);
        if (sub >= off) scan *= v;
    }
    float pre = __shfl_up(scan, 1, TPR);
    if (sub == 0) pre = 1.0f;

    orr *= pre; og *= pre; ob *= pre;
#pragma unroll
    for (int off = TPR / 2; off > 0; off >>= 1) {
        orr += __shfl_down(orr, off, TPR);
        og  += __shfl_down(og,  off, TPR);
        ob  += __shfl_down(ob,  off, TPR);
    }

    if (sub == 0) {
        out[ray * 3 + 0] = orr;
        out[ray * 3 + 1] = og;
        out[ray * 3 + 2] = ob;
    }
}

extern "C" void kernel_launch(void* const* d_in, const int* in_sizes, int n_in,
                              void* d_out, int out_size, void* d_ws, size_t ws_size,
                              hipStream_t stream) {
    const float* origins    = (const float*)d_in[0];
    const float* directions = (const float*)d_in[1];
    const float* nearp      = (const float*)d_in[2];
    const float* farp       = (const float*)d_in[3];
    const float* W1         = (const float*)d_in[4];
    const float* b1         = (const float*)d_in[5];
    const float* W2         = (const float*)d_in[6];
    const float* b2         = (const float*)d_in[7];
    float* out              = (float*)d_out;

    const int B     = in_sizes[0] / 3;       // 32768
    const int total = B * TPR;
    const int grid  = (total + BLOCK - 1) / BLOCK;

    nerf_fused<<<grid, BLOCK, 0, stream>>>(origins, directions, nearp, farp,
                                           W1, b1, W2, b2, out, B);
}

// Round 4
// 38.784 us; speedup vs baseline: 2.8320x; 2.8320x over previous
//
#include <hip/hip_runtime.h>

// NeRF fused render: B rays x S samples, MLP 3->64(relu)->4(exp), alpha composite.
// R4: packed-fp32 inner loop, spill-proof: all hot state in NAMED v2f scalars
// (no arrays -> nothing can be demoted to scratch), swizzles inline (op_sel).

typedef float v2f __attribute__((ext_vector_type(2)));

constexpr int S_TOTAL = 128;
constexpr int TPR     = 16;            // threads (lanes) per ray
constexpr int SPT     = S_TOTAL / TPR; // 8 samples per thread
constexpr int BLOCK   = 256;
constexpr int RPB     = BLOCK / TPR;   // 16 rays per block
constexpr int H       = 64;

__global__ __launch_bounds__(BLOCK, 6)
void nerf_fused(const float* __restrict__ origins,
                const float* __restrict__ directions,
                const float* __restrict__ nearp,
                const float* __restrict__ farp,
                const float* __restrict__ W1,   // [3][64]
                const float* __restrict__ b1,   // [64]
                const float* __restrict__ W2,   // [64][4]
                const float* __restrict__ b2,   // [4]
                float* __restrict__ out,        // [B][3]
                int B)
{
    // per-(ray,h) affine fold: ABs[r][h] = {A,B} with pre_h(m) = A + m*B
    __shared__ float ABs[RPB][H + 1][2];
    __shared__ float W2s[H][4];
    __shared__ float b2s[4];

    const int tid  = threadIdx.x;
    const int ray0 = blockIdx.x * RPB;

    if (tid < H) {
        W2s[tid][0] = W2[tid * 4 + 0];
        W2s[tid][1] = W2[tid * 4 + 1];
        W2s[tid][2] = W2[tid * 4 + 2];
        W2s[tid][3] = W2[tid * 4 + 3];
    }
    if (tid < 4) b2s[tid] = b2[tid];

#pragma unroll
    for (int idx = tid; idx < RPB * H; idx += BLOCK) {
        const int r   = idx >> 6;        // / H
        const int h   = idx & (H - 1);
        const int ray = ray0 + r;
        const float o0 = origins[ray * 3 + 0];
        const float o1 = origins[ray * 3 + 1];
        const float o2 = origins[ray * 3 + 2];
        float d0 = directions[ray * 3 + 0];
        float d1 = directions[ray * 3 + 1];
        float d2 = directions[ray * 3 + 2];
        const float nrm  = sqrtf(d0 * d0 + d1 * d1 + d2 * d2);
        const float rinv = 1.0f / fmaxf(nrm, 1e-12f);
        d0 *= rinv; d1 *= rinv; d2 *= rinv;
        const float w0 = W1[0 * H + h];
        const float w1 = W1[1 * H + h];
        const float w2 = W1[2 * H + h];
        ABs[r][h][0] = fmaf(o2, w2, fmaf(o1, w1, fmaf(o0, w0, b1[h])));
        ABs[r][h][1] = fmaf(d2, w2, fmaf(d1, w1, d0 * w0));
    }
    __syncthreads();

    const int sub  = tid & (TPR - 1);    // lane within ray group
    const int rloc = tid >> 4;           // local ray index (log2(TPR)=4)
    const int ray  = ray0 + rloc;

    const float nr    = nearp[0];
    const float fr    = farp[0];
    const float delta = (fr - nr) * (1.0f / (float)S_TOTAL);

    // sample-pair midpoints (named, not arrays)
    const float sbase = (float)(sub * SPT) + 0.5f;
    const v2f mp0 = (v2f){fmaf(sbase + 0.0f, delta, nr), fmaf(sbase + 1.0f, delta, nr)};
    const v2f mp1 = (v2f){fmaf(sbase + 2.0f, delta, nr), fmaf(sbase + 3.0f, delta, nr)};
    const v2f mp2 = (v2f){fmaf(sbase + 4.0f, delta, nr), fmaf(sbase + 5.0f, delta, nr)};
    const v2f mp3 = (v2f){fmaf(sbase + 6.0f, delta, nr), fmaf(sbase + 7.0f, delta, nr)};

    // acc[channel][pair] as named scalars
    const v2f bc0 = (v2f){b2s[0], b2s[0]};
    const v2f bc1 = (v2f){b2s[1], b2s[1]};
    const v2f bc2 = (v2f){b2s[2], b2s[2]};
    const v2f bc3 = (v2f){b2s[3], b2s[3]};
    v2f a0p0 = bc0, a0p1 = bc0, a0p2 = bc0, a0p3 = bc0;
    v2f a1p0 = bc1, a1p1 = bc1, a1p2 = bc1, a1p3 = bc1;
    v2f a2p0 = bc2, a2p1 = bc2, a2p2 = bc2, a2p3 = bc2;
    v2f a3p0 = bc3, a3p1 = bc3, a3p2 = bc3, a3p3 = bc3;

    const v2f vzero = (v2f){0.0f, 0.0f};

#pragma unroll 4
    for (int h = 0; h < H; ++h) {
        const v2f ab  = *reinterpret_cast<const v2f*>(&ABs[rloc][h][0]); // {A,B}
        const v2f w01 = *reinterpret_cast<const v2f*>(&W2s[h][0]);
        const v2f w23 = *reinterpret_cast<const v2f*>(&W2s[h][2]);

#define NERF_STEP(MP, A0, A1, A2, A3)                                         \
        {                                                                     \
            v2f hp = __builtin_elementwise_fma(MP, ab.yy, ab.xx);             \
            hp = __builtin_elementwise_max(hp, vzero);                        \
            A0 = __builtin_elementwise_fma(hp, w01.xx, A0);                   \
            A1 = __builtin_elementwise_fma(hp, w01.yy, A1);                   \
            A2 = __builtin_elementwise_fma(hp, w23.xx, A2);                   \
            A3 = __builtin_elementwise_fma(hp, w23.yy, A3);                   \
        }
        NERF_STEP(mp0, a0p0, a1p0, a2p0, a3p0)
        NERF_STEP(mp1, a0p1, a1p1, a2p1, a3p1)
        NERF_STEP(mp2, a0p2, a1p2, a2p2, a3p2)
        NERF_STEP(mp3, a0p3, a1p3, a2p3, a3p3)
#undef NERF_STEP
    }

    // local (in-order) composite over this lane's 8 samples
    float Tloc = 1.0f, orr = 0.0f, og = 0.0f, ob = 0.0f;
#define NERF_COMP1(CR, CG, CB, SG)                                            \
    {                                                                         \
        const float sig = __expf(SG);                                         \
        const float e   = __expf(-sig * delta);  /* = 1 - alpha */            \
        Tloc *= e;                                                            \
        const float w = Tloc * (1.0f - e);       /* T * alpha */              \
        orr = fmaf(w, __expf(CR), orr);                                       \
        og  = fmaf(w, __expf(CG), og);                                        \
        ob  = fmaf(w, __expf(CB), ob);                                        \
    }
    NERF_COMP1(a0p0.x, a1p0.x, a2p0.x, a3p0.x)
    NERF_COMP1(a0p0.y, a1p0.y, a2p0.y, a3p0.y)
    NERF_COMP1(a0p1.x, a1p1.x, a2p1.x, a3p1.x)
    NERF_COMP1(a0p1.y, a1p1.y, a2p1.y, a3p1.y)
    NERF_COMP1(a0p2.x, a1p2.x, a2p2.x, a3p2.x)
    NERF_COMP1(a0p2.y, a1p2.y, a2p2.y, a3p2.y)
    NERF_COMP1(a0p3.x, a1p3.x, a2p3.x, a3p3.x)
    NERF_COMP1(a0p3.y, a1p3.y, a2p3.y, a3p3.y)
#undef NERF_COMP1

    // stitch across the 16 lanes of this ray:
    // inclusive scan-product of Tloc, then exclusive prefix for scaling
    float scan = Tloc;
#pragma unroll
    for (int off = 1; off < TPR; off <<= 1) {
        const float v = __shfl_up(scan, off, TPR);
        if (sub >= off) scan *= v;
    }
    float pre = __shfl_up(scan, 1, TPR);
    if (sub == 0) pre = 1.0f;

    orr *= pre; og *= pre; ob *= pre;
#pragma unroll
    for (int off = TPR / 2; off > 0; off >>= 1) {
        orr += __shfl_down(orr, off, TPR);
        og  += __shfl_down(og,  off, TPR);
        ob  += __shfl_down(ob,  off, TPR);
    }

    if (sub == 0) {
        out[ray * 3 + 0] = orr;
        out[ray * 3 + 1] = og;
        out[ray * 3 + 2] = ob;
    }
}

extern "C" void kernel_launch(void* const* d_in, const int* in_sizes, int n_in,
                              void* d_out, int out_size, void* d_ws, size_t ws_size,
                              hipStream_t stream) {
    const float* origins    = (const float*)d_in[0];
    const float* directions = (const float*)d_in[1];
    const float* nearp      = (const float*)d_in[2];
    const float* farp       = (const float*)d_in[3];
    const float* W1         = (const float*)d_in[4];
    const float* b1         = (const float*)d_in[5];
    const float* W2         = (const float*)d_in[6];
    const float* b2         = (const float*)d_in[7];
    float* out              = (float*)d_out;

    const int B     = in_sizes[0] / 3;       // 32768
    const int total = B * TPR;
    const int grid  = (total + BLOCK - 1) / BLOCK;

    nerf_fused<<<grid, BLOCK, 0, stream>>>(origins, directions, nearp, farp,
                                           W1, b1, W2, b2, out, B);
}